// Round 1
// baseline (226.128 us; speedup 1.0000x reference)
//
#include <hip/hip_runtime.h>
#include <hip/hip_bf16.h>

// Causal SDPA: B=4,H=16,S=2048,D=64, fp32 in/out, softmax(QK^T/8) @ V.
// Flash-attention, bf16 MFMA 16x16x32, swapped-QK^T + permuted-K-staging so
// P feeds PV directly (no cross-lane fixup).

#define SEQ 2048
#define HD  64

typedef __attribute__((ext_vector_type(8))) short short8;
typedef __attribute__((ext_vector_type(4))) float f32x4;

__device__ __forceinline__ short f2bf(float f) {
    union { float f; unsigned u; } x; x.f = f;
    unsigned r = x.u + 0x7fff + ((x.u >> 16) & 1);   // RNE to bf16
    return (short)(r >> 16);
}

__device__ __forceinline__ short8 pack8(f32x4 a, f32x4 b, float s) {
    short8 t;
    t[0]=f2bf(a[0]*s); t[1]=f2bf(a[1]*s); t[2]=f2bf(a[2]*s); t[3]=f2bf(a[3]*s);
    t[4]=f2bf(b[0]*s); t[5]=f2bf(b[1]*s); t[6]=f2bf(b[2]*s); t[7]=f2bf(b[3]*s);
    return t;
}

// LDS layout: K tile [32][72] bf16 (rows permuted), V^T tile [64][40] bf16.
// Epilogue reuses the same memory as per-wave [16][68] f32 transpose buffers.
#define KLD 72
#define VLD 40
#define ELD 68

__global__ __launch_bounds__(256, 4) void sdpa_kernel(
    const float* __restrict__ Q, const float* __restrict__ K,
    const float* __restrict__ V, float* __restrict__ O)
{
    __shared__ __align__(16) char smraw[4 * 16 * ELD * 4];  // 17408 B
    short* Klds = (short*)smraw;                   // 32*72*2 = 4608
    short* Vlds = (short*)(smraw + 4608);          // 64*40*2 = 5120

    const int bx = blockIdx.x;
    const int qt = 31 - (bx >> 6);        // heavy (high-qt) blocks first
    const int bh = bx & 63;
    const int qbase = qt * 64;

    const int tid  = threadIdx.x;
    const int lane = tid & 63;
    const int w    = tid >> 6;
    const int g    = lane >> 4;
    const int r16  = lane & 15;
    const int wq   = qbase + w * 16;      // wave's first q row
    const int qrow = wq + r16;            // this lane's q row (B-col)

    // ---- Q fragments, pre-scaled by 1/sqrt(64)=0.125 (exact in bf16) ----
    short8 qf[2];
    {
        const float* qp = Q + (size_t)(bh * SEQ + qrow) * HD + 8 * g;
        #pragma unroll
        for (int c = 0; c < 2; ++c) {
            f32x4 a = *(const f32x4*)(qp + c * 32);
            f32x4 b = *(const f32x4*)(qp + c * 32 + 4);
            qf[c] = pack8(a, b, 0.125f);
        }
    }

    f32x4 oacc[4] = {};          // O^T tiles: d = dt*16+4g+r, q = r16
    float mrun = -1e30f, lrun = 0.0f;

    const int nkvb = (qbase + 64) >> 5;   // causal KV-block count for this block
    for (int kvb = 0; kvb < nkvb; ++kvb) {
        const int kvbase = kvb << 5;

        // ---- stage K tile, rows permuted: global o -> LDS row 16*((o>>2)&1)+4*(o>>3)+(o&3)
        {
            const int kvo = tid >> 3;
            const int dc  = (tid & 7) * 8;
            const float* kp = K + (size_t)(bh * SEQ + kvbase + kvo) * HD + dc;
            f32x4 a = *(const f32x4*)kp;
            f32x4 b = *(const f32x4*)(kp + 4);
            const int p = 16 * ((kvo >> 2) & 1) + 4 * (kvo >> 3) + (kvo & 3);
            *(short8*)&Klds[p * KLD + dc] = pack8(a, b, 1.0f);
        }
        // ---- stage V^T tile (natural kv order) ----
        {
            const int kvo = tid & 31;
            const int dc  = (tid >> 5) * 8;
            const float* vp = V + (size_t)(bh * SEQ + kvbase + kvo) * HD + dc;
            f32x4 a = *(const f32x4*)vp;
            f32x4 b = *(const f32x4*)(vp + 4);
            Vlds[(dc + 0) * VLD + kvo] = f2bf(a[0]);
            Vlds[(dc + 1) * VLD + kvo] = f2bf(a[1]);
            Vlds[(dc + 2) * VLD + kvo] = f2bf(a[2]);
            Vlds[(dc + 3) * VLD + kvo] = f2bf(a[3]);
            Vlds[(dc + 4) * VLD + kvo] = f2bf(b[0]);
            Vlds[(dc + 5) * VLD + kvo] = f2bf(b[1]);
            Vlds[(dc + 6) * VLD + kvo] = f2bf(b[2]);
            Vlds[(dc + 7) * VLD + kvo] = f2bf(b[3]);
        }
        __syncthreads();

        if (kvbase <= wq + 15) {          // wave-uniform causal skip
            // ---- scores: S^T = K . Q^T  (two 16-kv tiles, D=64 in 2 chunks) ----
            f32x4 sa[2];
            #pragma unroll
            for (int t = 0; t < 2; ++t) {
                f32x4 acc = {};
                #pragma unroll
                for (int c = 0; c < 2; ++c) {
                    short8 kf = *(const short8*)&Klds[(t * 16 + r16) * KLD + c * 32 + 8 * g];
                    acc = __builtin_amdgcn_mfma_f32_16x16x32_bf16(kf, qf[c], acc, 0, 0, 0);
                }
                sa[t] = acc;
            }
            // acc element (t,r) holds kv = kvbase + 8g + 4t + r, q = r16.
            if (kvbase + 31 > wq) {       // diagonal block: causal mask
                #pragma unroll
                for (int t = 0; t < 2; ++t)
                    #pragma unroll
                    for (int r = 0; r < 4; ++r) {
                        int kv = kvbase + 8 * g + 4 * t + r;
                        if (kv > qrow) sa[t][r] = -1e30f;
                    }
            }
            // ---- online softmax (stats per q=r16, lanes xor 16/32 share a row) ----
            float mloc = sa[0][0];
            #pragma unroll
            for (int t = 0; t < 2; ++t)
                #pragma unroll
                for (int r = 0; r < 4; ++r) mloc = fmaxf(mloc, sa[t][r]);
            mloc = fmaxf(mloc, __shfl_xor(mloc, 16));
            mloc = fmaxf(mloc, __shfl_xor(mloc, 32));
            float mnew = fmaxf(mrun, mloc);
            float alpha = __expf(mrun - mnew);
            float ls = 0.0f;
            #pragma unroll
            for (int t = 0; t < 2; ++t)
                #pragma unroll
                for (int r = 0; r < 4; ++r) {
                    float p = __expf(sa[t][r] - mnew);
                    sa[t][r] = p; ls += p;
                }
            ls += __shfl_xor(ls, 16);
            ls += __shfl_xor(ls, 32);
            lrun = lrun * alpha + ls;
            mrun = mnew;
            // ---- P fragment: element j=4t+r is kv=kvbase+8g+j -> direct B-frag ----
            short8 pf;
            pf[0] = f2bf(sa[0][0]); pf[1] = f2bf(sa[0][1]);
            pf[2] = f2bf(sa[0][2]); pf[3] = f2bf(sa[0][3]);
            pf[4] = f2bf(sa[1][0]); pf[5] = f2bf(sa[1][1]);
            pf[6] = f2bf(sa[1][2]); pf[7] = f2bf(sa[1][3]);
            // ---- PV: O^T += V^T . P ----
            #pragma unroll
            for (int dt = 0; dt < 4; ++dt) {
                f32x4 t2 = oacc[dt] * alpha;
                short8 vf = *(const short8*)&Vlds[(dt * 16 + r16) * VLD + 8 * g];
                oacc[dt] = __builtin_amdgcn_mfma_f32_16x16x32_bf16(vf, pf, t2, 0, 0, 0);
            }
        }
        __syncthreads();
    }

    // ---- epilogue: normalize, transpose through LDS, coalesced store ----
    const float inv = 1.0f / lrun;
    float* ep = (float*)smraw + w * (16 * ELD);
    #pragma unroll
    for (int dt = 0; dt < 4; ++dt)
        #pragma unroll
        for (int r = 0; r < 4; ++r)
            ep[r16 * ELD + dt * 16 + 4 * g + r] = oacc[dt][r] * inv;
    __syncthreads();

    const int qr = lane >> 2;
    const int cb = (lane & 3) * 16;
    const float* eprow = ep + qr * ELD + cb;
    float* op = O + (size_t)(bh * SEQ + wq + qr) * HD + cb;
    #pragma unroll
    for (int i = 0; i < 4; ++i)
        *(f32x4*)(op + 4 * i) = *(const f32x4*)(eprow + 4 * i);
}

extern "C" void kernel_launch(void* const* d_in, const int* in_sizes, int n_in,
                              void* d_out, int out_size, void* d_ws, size_t ws_size,
                              hipStream_t stream) {
    (void)in_sizes; (void)n_in; (void)out_size; (void)d_ws; (void)ws_size;
    const float* q = (const float*)d_in[0];
    const float* k = (const float*)d_in[1];
    const float* v = (const float*)d_in[2];
    float* o = (float*)d_out;
    // grid: 64 bh * 32 q-tiles; qt reversed inside kernel so heavy blocks go first
    sdpa_kernel<<<dim3(64 * 32), dim3(256), 0, stream>>>(q, k, v, o);
}

// Round 3
// 224.050 us; speedup vs baseline: 1.0093x; 1.0093x over previous
//
#include <hip/hip_runtime.h>

// Causal SDPA: B=4,H=16,S=2048,D=64, fp32 in/out.
// Flash attention, bf16 mfma 16x16x32, swapped QK^T (S^T = K.Q) with permuted
// K staging so P feeds PV directly. 32 q-rows/wave, KVBLK=64, exp2-domain
// softmax, XOR-swizzled 16B-cell LDS (conflict-free). No inline asm, no
// forced-spill launch bounds (round-2 replay-divergence suspects removed).

#define SEQ 2048
#define HD  64

typedef __attribute__((ext_vector_type(8))) short short8;
typedef __attribute__((ext_vector_type(4))) float f32x4;

__device__ __forceinline__ unsigned f2bfu(float f) {
    union { float f; unsigned u; } x; x.f = f;
    return (x.u + 0x7fff + ((x.u >> 16) & 1)) >> 16;   // RNE, result in [0,0xffff]
}
__device__ __forceinline__ unsigned pk2(float lo, float hi) {
    return f2bfu(lo) | (f2bfu(hi) << 16);
}

// LDS: K and V^T tiles, each 64 rows x 8 cells of 16B (8 bf16), XOR-swizzled:
// cell address = (row*8 + (unit ^ (row&7))) * 16  -> conflict-free reads+writes
__global__ __launch_bounds__(256, 2) void sdpa_kernel(
    const float* __restrict__ Q, const float* __restrict__ K,
    const float* __restrict__ V, float* __restrict__ O)
{
    __shared__ __align__(16) char smraw[16384];
    char* Kl = smraw;            // 8192 B
    char* Vl = smraw + 8192;     // 8192 B

    const int bx = blockIdx.x;
    const int qt = 15 - (bx >> 6);        // heavy blocks first
    const int bh = bx & 63;
    const int qbase = qt * 128;           // 128 q rows per block

    const int tid  = threadIdx.x;
    const int lane = tid & 63;
    const int w    = tid >> 6;
    const int g    = lane >> 4;
    const int r16  = lane & 15;
    const int wq   = qbase + w * 32;      // wave's first q row (32 rows/wave)

    const size_t base = (size_t)bh * (SEQ * HD);

    // ---- Q fragments, pre-scaled by 0.125*log2(e) (exp2-domain softmax) ----
    const float SC = 0.18033688011112042f;
    short8 qf[2][2];                      // [qsub][k-chunk]
    #pragma unroll
    for (int qs = 0; qs < 2; ++qs) {
        const float* qp = Q + base + (size_t)(wq + qs * 16 + r16) * HD + 8 * g;
        #pragma unroll
        for (int c = 0; c < 2; ++c) {
            f32x4 a = *(const f32x4*)(qp + c * 32);
            f32x4 b = *(const f32x4*)(qp + c * 32 + 4);
            union { short8 s; unsigned u[4]; } t;
            t.u[0] = pk2(a[0] * SC, a[1] * SC);
            t.u[1] = pk2(a[2] * SC, a[3] * SC);
            t.u[2] = pk2(b[0] * SC, b[1] * SC);
            t.u[3] = pk2(b[2] * SC, b[3] * SC);
            qf[qs][c] = t.s;
        }
    }

    f32x4 oacc[2][4] = {};                // [qsub][dt]: d=dt*16+4g+r, q=r16
    float mrun[2] = {-1e30f, -1e30f};
    float lrun[2] = {0.0f, 0.0f};

    // staging assignments (fixed per thread)
    const int k_kvo = tid >> 2;                      // K row 0..63
    const int k_o   = k_kvo & 31;
    const int k_row = (k_kvo & 32) + 16 * ((k_o >> 2) & 1) + 4 * (k_o >> 3) + (k_o & 3);
    const int k_dc  = (tid & 3) * 2;                 // first d-cell unit
    const int v_kv0 = (tid & 31) * 2;                // kv pair
    const int v_db  = (tid >> 5) * 8;                // 8 d rows

    const int nkvb = (qbase + 128) >> 6;
    for (int kvb = 0; kvb < nkvb; ++kvb) {
        const int kvbase = kvb << 6;

        // ---- stage K (row-permuted, 2x ds_write_b128) ----
        {
            const float* kp = K + base + (size_t)(kvbase + k_kvo) * HD + k_dc * 8;
            f32x4 a0 = *(const f32x4*)(kp + 0);
            f32x4 a1 = *(const f32x4*)(kp + 4);
            f32x4 b0 = *(const f32x4*)(kp + 8);
            f32x4 b1 = *(const f32x4*)(kp + 12);
            union { short8 s; unsigned u[4]; } c0, c1;
            c0.u[0] = pk2(a0[0], a0[1]); c0.u[1] = pk2(a0[2], a0[3]);
            c0.u[2] = pk2(a1[0], a1[1]); c0.u[3] = pk2(a1[2], a1[3]);
            c1.u[0] = pk2(b0[0], b0[1]); c1.u[1] = pk2(b0[2], b0[3]);
            c1.u[2] = pk2(b1[0], b1[1]); c1.u[3] = pk2(b1[2], b1[3]);
            const int r7 = k_row & 7;
            *(short8*)(Kl + ((k_row * 8 + (k_dc ^ r7)) << 4))       = c0.s;
            *(short8*)(Kl + ((k_row * 8 + ((k_dc + 1) ^ r7)) << 4)) = c1.s;
        }
        // ---- stage V^T (paired kv -> ds_write_b32, conflict-free) ----
        {
            const float* vp = V + base + (size_t)(kvbase + v_kv0) * HD + v_db;
            f32x4 a0 = *(const f32x4*)(vp + 0);
            f32x4 a1 = *(const f32x4*)(vp + 4);
            f32x4 b0 = *(const f32x4*)(vp + HD);
            f32x4 b1 = *(const f32x4*)(vp + HD + 4);
            const int u  = v_kv0 >> 3;
            const int wo = (v_kv0 & 7) * 2;
            #pragma unroll
            for (int i = 0; i < 4; ++i) {
                const int d = v_db + i;
                *(unsigned*)(Vl + ((d * 8 + (u ^ (d & 7))) << 4) + wo) = pk2(a0[i], b0[i]);
            }
            #pragma unroll
            for (int i = 0; i < 4; ++i) {
                const int d = v_db + 4 + i;
                *(unsigned*)(Vl + ((d * 8 + (u ^ (d & 7))) << 4) + wo) = pk2(a1[i], b1[i]);
            }
        }
        __syncthreads();

        if (kvbase <= wq + 31) {          // wave-uniform causal activity
            // ---- QK^T for both q-subtiles, sharing K fragment reads ----
            f32x4 sa[2][2][2];            // [qsub][c2][t]; kv=kvbase+32c2+8g+4t+r, q=r16
            #pragma unroll
            for (int qs = 0; qs < 2; ++qs)
                #pragma unroll
                for (int c2 = 0; c2 < 2; ++c2)
                    #pragma unroll
                    for (int t = 0; t < 2; ++t)
                        sa[qs][c2][t] = (f32x4){0.f, 0.f, 0.f, 0.f};
            #pragma unroll
            for (int c2 = 0; c2 < 2; ++c2)
                #pragma unroll
                for (int t = 0; t < 2; ++t)
                    #pragma unroll
                    for (int c = 0; c < 2; ++c) {
                        const int row = c2 * 32 + t * 16 + r16;
                        short8 kf = *(const short8*)(Kl + ((row * 8 + ((4 * c + g) ^ (row & 7))) << 4));
                        sa[0][c2][t] = __builtin_amdgcn_mfma_f32_16x16x32_bf16(kf, qf[0][c], sa[0][c2][t], 0, 0, 0);
                        sa[1][c2][t] = __builtin_amdgcn_mfma_f32_16x16x32_bf16(kf, qf[1][c], sa[1][c2][t], 0, 0, 0);
                    }

            // ---- mask + online softmax (exp2 domain) per q-subtile ----
            #pragma unroll
            for (int qs = 0; qs < 2; ++qs) {
                const int q0 = wq + qs * 16;
                const int qrow = q0 + r16;
                if (kvbase + 63 > q0) {   // diagonal region: causal mask
                    #pragma unroll
                    for (int c2 = 0; c2 < 2; ++c2)
                        #pragma unroll
                        for (int t = 0; t < 2; ++t)
                            #pragma unroll
                            for (int r = 0; r < 4; ++r) {
                                const int kv = kvbase + c2 * 32 + 8 * g + 4 * t + r;
                                if (kv > qrow) sa[qs][c2][t][r] = -1e30f;
                            }
                }
                float mloc = sa[qs][0][0][0];
                #pragma unroll
                for (int c2 = 0; c2 < 2; ++c2)
                    #pragma unroll
                    for (int t = 0; t < 2; ++t)
                        #pragma unroll
                        for (int r = 0; r < 4; ++r)
                            mloc = fmaxf(mloc, sa[qs][c2][t][r]);
                mloc = fmaxf(mloc, __shfl_xor(mloc, 16));
                mloc = fmaxf(mloc, __shfl_xor(mloc, 32));
                const float mnew  = fmaxf(mrun[qs], mloc);
                const float alpha = __builtin_amdgcn_exp2f(mrun[qs] - mnew);
                float ls = 0.0f;
                #pragma unroll
                for (int c2 = 0; c2 < 2; ++c2)
                    #pragma unroll
                    for (int t = 0; t < 2; ++t)
                        #pragma unroll
                        for (int r = 0; r < 4; ++r) {
                            const float p = __builtin_amdgcn_exp2f(sa[qs][c2][t][r] - mnew);
                            sa[qs][c2][t][r] = p;
                            ls += p;
                        }
                ls += __shfl_xor(ls, 16);
                ls += __shfl_xor(ls, 32);
                lrun[qs] = lrun[qs] * alpha + ls;
                mrun[qs] = mnew;
                #pragma unroll
                for (int dt = 0; dt < 4; ++dt) oacc[qs][dt] *= alpha;
            }

            // ---- PV: O^T += V^T . P, sharing V fragment reads ----
            #pragma unroll
            for (int c2 = 0; c2 < 2; ++c2) {
                union { short8 s; unsigned u[4]; } pf0, pf1;
                pf0.u[0] = pk2(sa[0][c2][0][0], sa[0][c2][0][1]);
                pf0.u[1] = pk2(sa[0][c2][0][2], sa[0][c2][0][3]);
                pf0.u[2] = pk2(sa[0][c2][1][0], sa[0][c2][1][1]);
                pf0.u[3] = pk2(sa[0][c2][1][2], sa[0][c2][1][3]);
                pf1.u[0] = pk2(sa[1][c2][0][0], sa[1][c2][0][1]);
                pf1.u[1] = pk2(sa[1][c2][0][2], sa[1][c2][0][3]);
                pf1.u[2] = pk2(sa[1][c2][1][0], sa[1][c2][1][1]);
                pf1.u[3] = pk2(sa[1][c2][1][2], sa[1][c2][1][3]);
                #pragma unroll
                for (int dt = 0; dt < 4; ++dt) {
                    const int row = dt * 16 + r16;
                    short8 vf = *(const short8*)(Vl + ((row * 8 + ((c2 * 4 + g) ^ (row & 7))) << 4));
                    oacc[0][dt] = __builtin_amdgcn_mfma_f32_16x16x32_bf16(vf, pf0.s, oacc[0][dt], 0, 0, 0);
                    oacc[1][dt] = __builtin_amdgcn_mfma_f32_16x16x32_bf16(vf, pf1.s, oacc[1][dt], 0, 0, 0);
                }
            }
        }
        __syncthreads();
    }

    // ---- epilogue: direct stores (d=dt*16+4g+r contiguous per reg quad) ----
    #pragma unroll
    for (int qs = 0; qs < 2; ++qs) {
        const float inv = 1.0f / lrun[qs];
        float* op = O + base + (size_t)(wq + qs * 16 + r16) * HD + 4 * g;
        #pragma unroll
        for (int dt = 0; dt < 4; ++dt) {
            f32x4 vv = oacc[qs][dt] * inv;
            *(f32x4*)(op + dt * 16) = vv;
        }
    }
}

extern "C" void kernel_launch(void* const* d_in, const int* in_sizes, int n_in,
                              void* d_out, int out_size, void* d_ws, size_t ws_size,
                              hipStream_t stream) {
    (void)in_sizes; (void)n_in; (void)out_size; (void)d_ws; (void)ws_size;
    const float* q = (const float*)d_in[0];
    const float* k = (const float*)d_in[1];
    const float* v = (const float*)d_in[2];
    float* o = (float*)d_out;
    sdpa_kernel<<<dim3(64 * 16), dim3(256), 0, stream>>>(q, k, v, o);
}

// Round 4
// 202.239 us; speedup vs baseline: 1.1181x; 1.1078x over previous
//
#include <hip/hip_runtime.h>

// Causal SDPA: B=4,H=16,S=2048,D=64, fp32 in/out.
// Flash attention, bf16 mfma 16x16x32, swapped QK^T (S^T = K.Q) with permuted
// K staging so P feeds PV directly. 32 q-rows/wave, KVBLK=64, exp2-domain
// softmax, XOR-swizzled 16B-cell LDS (conflict-free).
// Round 4: double-buffered LDS + prefetch-to-regs (issue loads before compute,
// write LDS after), 1 barrier/iter, defer-rescale (THR=8), setprio on MFMA.

#define SEQ 2048
#define HD  64

typedef __attribute__((ext_vector_type(8))) short short8;
typedef __attribute__((ext_vector_type(4))) float f32x4;

__device__ __forceinline__ unsigned f2bfu(float f) {
    union { float f; unsigned u; } x; x.f = f;
    return (x.u + 0x7fff + ((x.u >> 16) & 1)) >> 16;   // RNE
}
__device__ __forceinline__ unsigned pk2(float lo, float hi) {
    return f2bfu(lo) | (f2bfu(hi) << 16);
}

// Per buffer: K tile 8192 B + V^T tile 8192 B. Cells are 16 B (8 bf16),
// XOR-swizzled: cell addr = (row*8 + (unit ^ (row&7))) * 16.
__global__ __launch_bounds__(256, 2) void sdpa_kernel(
    const float* __restrict__ Q, const float* __restrict__ K,
    const float* __restrict__ V, float* __restrict__ O)
{
    __shared__ __align__(16) char smraw[32768];

    const int bx = blockIdx.x;
    const int qt = 15 - (bx >> 6);        // heavy blocks first
    const int bh = bx & 63;
    const int qbase = qt * 128;

    const int tid  = threadIdx.x;
    const int lane = tid & 63;
    const int w    = tid >> 6;
    const int g    = lane >> 4;
    const int r16  = lane & 15;
    const int wq   = qbase + w * 32;

    const size_t base = (size_t)bh * (SEQ * HD);

    // ---- Q fragments, pre-scaled by 0.125*log2(e) ----
    const float SC = 0.18033688011112042f;
    short8 qf[2][2];
    #pragma unroll
    for (int qs = 0; qs < 2; ++qs) {
        const float* qp = Q + base + (size_t)(wq + qs * 16 + r16) * HD + 8 * g;
        #pragma unroll
        for (int c = 0; c < 2; ++c) {
            f32x4 a = *(const f32x4*)(qp + c * 32);
            f32x4 b = *(const f32x4*)(qp + c * 32 + 4);
            union { short8 s; unsigned u[4]; } t;
            t.u[0] = pk2(a[0] * SC, a[1] * SC);
            t.u[1] = pk2(a[2] * SC, a[3] * SC);
            t.u[2] = pk2(b[0] * SC, b[1] * SC);
            t.u[3] = pk2(b[2] * SC, b[3] * SC);
            qf[qs][c] = t.s;
        }
    }

    f32x4 oacc[2][4] = {};
    float mrun[2] = {-1e30f, -1e30f};
    float lrun[2] = {0.0f, 0.0f};

    // staging thread assignments
    const int k_kvo = tid >> 2;
    const int k_o   = k_kvo & 31;
    const int k_row = (k_kvo & 32) + 16 * ((k_o >> 2) & 1) + 4 * (k_o >> 3) + (k_o & 3);
    const int k_dc  = (tid & 3) * 2;
    const int v_kv0 = (tid & 31) * 2;
    const int v_db  = (tid >> 5) * 8;

    // prefetch registers (held across compute)
    f32x4 ka0, ka1, kb0, kb1, va0, va1, vb0, vb1;

    auto LOADT = [&](int kvbase) {
        const float* kp = K + base + (size_t)(kvbase + k_kvo) * HD + k_dc * 8;
        ka0 = *(const f32x4*)(kp + 0);
        ka1 = *(const f32x4*)(kp + 4);
        kb0 = *(const f32x4*)(kp + 8);
        kb1 = *(const f32x4*)(kp + 12);
        const float* vp = V + base + (size_t)(kvbase + v_kv0) * HD + v_db;
        va0 = *(const f32x4*)(vp + 0);
        va1 = *(const f32x4*)(vp + 4);
        vb0 = *(const f32x4*)(vp + HD);
        vb1 = *(const f32x4*)(vp + HD + 4);
    };
    auto WRITET = [&](int b) {
        char* Kl = smraw + b * 16384;
        char* Vl = Kl + 8192;
        union { short8 s; unsigned u[4]; } c0, c1;
        c0.u[0] = pk2(ka0[0], ka0[1]); c0.u[1] = pk2(ka0[2], ka0[3]);
        c0.u[2] = pk2(ka1[0], ka1[1]); c0.u[3] = pk2(ka1[2], ka1[3]);
        c1.u[0] = pk2(kb0[0], kb0[1]); c1.u[1] = pk2(kb0[2], kb0[3]);
        c1.u[2] = pk2(kb1[0], kb1[1]); c1.u[3] = pk2(kb1[2], kb1[3]);
        const int r7 = k_row & 7;
        *(short8*)(Kl + ((k_row * 8 + (k_dc ^ r7)) << 4))       = c0.s;
        *(short8*)(Kl + ((k_row * 8 + ((k_dc + 1) ^ r7)) << 4)) = c1.s;
        const int u  = v_kv0 >> 3;
        const int wo = (v_kv0 & 7) * 2;
        #pragma unroll
        for (int i = 0; i < 4; ++i) {
            const int d = v_db + i;
            *(unsigned*)(Vl + ((d * 8 + (u ^ (d & 7))) << 4) + wo) = pk2(va0[i], vb0[i]);
        }
        #pragma unroll
        for (int i = 0; i < 4; ++i) {
            const int d = v_db + 4 + i;
            *(unsigned*)(Vl + ((d * 8 + (u ^ (d & 7))) << 4) + wo) = pk2(va1[i], vb1[i]);
        }
    };

    const int nkvb = (qbase + 128) >> 6;

    // prologue: stage tile 0
    LOADT(0);
    WRITET(0);
    __syncthreads();

    for (int kvb = 0; kvb < nkvb; ++kvb) {
        const int kvbase = kvb << 6;
        const int buf = kvb & 1;
        const bool more = (kvb + 1 < nkvb);

        if (more) LOADT((kvb + 1) << 6);   // issue prefetch loads early

        if (kvbase <= wq + 31) {           // wave-uniform causal activity
            const char* Kl = smraw + buf * 16384;
            const char* Vl = Kl + 8192;

            // ---- QK^T (shared K-fragment reads across q-subtiles) ----
            f32x4 sa[2][2][2];
            #pragma unroll
            for (int qs = 0; qs < 2; ++qs)
                #pragma unroll
                for (int c2 = 0; c2 < 2; ++c2)
                    #pragma unroll
                    for (int t = 0; t < 2; ++t)
                        sa[qs][c2][t] = (f32x4){0.f, 0.f, 0.f, 0.f};
            __builtin_amdgcn_s_setprio(1);
            #pragma unroll
            for (int c2 = 0; c2 < 2; ++c2)
                #pragma unroll
                for (int t = 0; t < 2; ++t)
                    #pragma unroll
                    for (int c = 0; c < 2; ++c) {
                        const int row = c2 * 32 + t * 16 + r16;
                        short8 kf = *(const short8*)(Kl + ((row * 8 + ((4 * c + g) ^ (row & 7))) << 4));
                        sa[0][c2][t] = __builtin_amdgcn_mfma_f32_16x16x32_bf16(kf, qf[0][c], sa[0][c2][t], 0, 0, 0);
                        sa[1][c2][t] = __builtin_amdgcn_mfma_f32_16x16x32_bf16(kf, qf[1][c], sa[1][c2][t], 0, 0, 0);
                    }
            __builtin_amdgcn_s_setprio(0);

            // ---- mask (diagonal region only) ----
            #pragma unroll
            for (int qs = 0; qs < 2; ++qs) {
                const int q0 = wq + qs * 16;
                if (kvbase + 63 > q0) {
                    const int qrow = q0 + r16;
                    #pragma unroll
                    for (int c2 = 0; c2 < 2; ++c2)
                        #pragma unroll
                        for (int t = 0; t < 2; ++t)
                            #pragma unroll
                            for (int r = 0; r < 4; ++r) {
                                const int kv = kvbase + c2 * 32 + 8 * g + 4 * t + r;
                                if (kv > qrow) sa[qs][c2][t][r] = -1e30f;
                            }
                }
            }

            // ---- online softmax stats; defer-rescale (exp2 domain, THR=8) ----
            float mnew[2];
            #pragma unroll
            for (int qs = 0; qs < 2; ++qs) {
                float mloc = sa[qs][0][0][0];
                #pragma unroll
                for (int c2 = 0; c2 < 2; ++c2)
                    #pragma unroll
                    for (int t = 0; t < 2; ++t)
                        #pragma unroll
                        for (int r = 0; r < 4; ++r)
                            mloc = fmaxf(mloc, sa[qs][c2][t][r]);
                mloc = fmaxf(mloc, __shfl_xor(mloc, 16));
                mloc = fmaxf(mloc, __shfl_xor(mloc, 32));
                mnew[qs] = fmaxf(mrun[qs], mloc);
            }
            if (!__all((mnew[0] - mrun[0] <= 8.0f) && (mnew[1] - mrun[1] <= 8.0f))) {
                #pragma unroll
                for (int qs = 0; qs < 2; ++qs) {
                    const float alpha = __builtin_amdgcn_exp2f(mrun[qs] - mnew[qs]);
                    lrun[qs] *= alpha;
                    mrun[qs] = mnew[qs];
                    #pragma unroll
                    for (int dt = 0; dt < 4; ++dt) oacc[qs][dt] *= alpha;
                }
            }
            #pragma unroll
            for (int qs = 0; qs < 2; ++qs) {
                float ls = 0.0f;
                #pragma unroll
                for (int c2 = 0; c2 < 2; ++c2)
                    #pragma unroll
                    for (int t = 0; t < 2; ++t)
                        #pragma unroll
                        for (int r = 0; r < 4; ++r) {
                            const float p = __builtin_amdgcn_exp2f(sa[qs][c2][t][r] - mrun[qs]);
                            sa[qs][c2][t][r] = p;
                            ls += p;
                        }
                ls += __shfl_xor(ls, 16);
                ls += __shfl_xor(ls, 32);
                lrun[qs] += ls;
            }

            // ---- PV: O^T += V^T . P (shared V-fragment reads) ----
            #pragma unroll
            for (int c2 = 0; c2 < 2; ++c2) {
                union { short8 s; unsigned u[4]; } pf0, pf1;
                pf0.u[0] = pk2(sa[0][c2][0][0], sa[0][c2][0][1]);
                pf0.u[1] = pk2(sa[0][c2][0][2], sa[0][c2][0][3]);
                pf0.u[2] = pk2(sa[0][c2][1][0], sa[0][c2][1][1]);
                pf0.u[3] = pk2(sa[0][c2][1][2], sa[0][c2][1][3]);
                pf1.u[0] = pk2(sa[1][c2][0][0], sa[1][c2][0][1]);
                pf1.u[1] = pk2(sa[1][c2][0][2], sa[1][c2][0][3]);
                pf1.u[2] = pk2(sa[1][c2][1][0], sa[1][c2][1][1]);
                pf1.u[3] = pk2(sa[1][c2][1][2], sa[1][c2][1][3]);
                __builtin_amdgcn_s_setprio(1);
                #pragma unroll
                for (int dt = 0; dt < 4; ++dt) {
                    const int row = dt * 16 + r16;
                    short8 vf = *(const short8*)(Vl + ((row * 8 + ((c2 * 4 + g) ^ (row & 7))) << 4));
                    oacc[0][dt] = __builtin_amdgcn_mfma_f32_16x16x32_bf16(vf, pf0.s, oacc[0][dt], 0, 0, 0);
                    oacc[1][dt] = __builtin_amdgcn_mfma_f32_16x16x32_bf16(vf, pf1.s, oacc[1][dt], 0, 0, 0);
                }
                __builtin_amdgcn_s_setprio(0);
            }
        }

        if (more) {
            WRITET(buf ^ 1);               // cvt+write prefetched tile
            __syncthreads();
        }
    }

    // ---- epilogue: direct coalesced stores from the accumulator ----
    #pragma unroll
    for (int qs = 0; qs < 2; ++qs) {
        const float inv = 1.0f / lrun[qs];
        float* op = O + base + (size_t)(wq + qs * 16 + r16) * HD + 4 * g;
        #pragma unroll
        for (int dt = 0; dt < 4; ++dt) {
            f32x4 vv = oacc[qs][dt] * inv;
            *(f32x4*)(op + dt * 16) = vv;
        }
    }
}

extern "C" void kernel_launch(void* const* d_in, const int* in_sizes, int n_in,
                              void* d_out, int out_size, void* d_ws, size_t ws_size,
                              hipStream_t stream) {
    (void)in_sizes; (void)n_in; (void)out_size; (void)d_ws; (void)ws_size;
    const float* q = (const float*)d_in[0];
    const float* k = (const float*)d_in[1];
    const float* v = (const float*)d_in[2];
    float* o = (float*)d_out;
    sdpa_kernel<<<dim3(64 * 16), dim3(256), 0, stream>>>(q, k, v, o);
}

// Round 6
// 183.703 us; speedup vs baseline: 1.2309x; 1.1009x over previous
//
#include <hip/hip_runtime.h>

// Causal SDPA: B=4,H=16,S=2048,D=64, fp32 in/out.
// Flash attention, bf16 mfma 16x16x32, swapped QK^T (S^T = K.Q) with permuted
// K staging so P feeds PV directly. 32 q-rows/wave, KVBLK=64, exp2-domain
// softmax, XOR-swizzled 16B-cell LDS (conflict-free), double-buffered with
// prefetch-to-regs, 1 barrier/iter, defer-rescale, setprio on MFMA.
// Round 5: hardware v_cvt_pk_bf16_f32 via __builtin_convertvector, paired
// q-tiles (15-p, p) for uniform 34-iter blocks (kills the occupancy tail),
// row-sum l computed by MFMA with a ones fragment (replaces adds+shuffles).

#define SEQ 2048
#define HD  64

typedef __attribute__((ext_vector_type(8))) short short8;
typedef __attribute__((ext_vector_type(4))) float f32x4;
typedef __attribute__((ext_vector_type(2))) float f32x2;
typedef __attribute__((ext_vector_type(2))) __bf16 bf16x2;

__device__ __forceinline__ unsigned pk2(float lo, float hi) {
    union { bf16x2 v; unsigned u; } r;
    r.v = __builtin_convertvector((f32x2){lo, hi}, bf16x2);
    return r.u;
}

// Per buffer: K tile 8192 B + V^T tile 8192 B. Cells are 16 B (8 bf16),
// XOR-swizzled: cell addr = (row*8 + (unit ^ (row&7))) * 16.
__global__ __launch_bounds__(256, 2) void sdpa_kernel(
    const float* __restrict__ Q, const float* __restrict__ K,
    const float* __restrict__ V, float* __restrict__ O)
{
    __shared__ __align__(16) char smraw[32768];

    const int bx = blockIdx.x;
    const int p  = bx >> 6;               // 0..7: pair (15-p, p)
    const int bh = bx & 63;

    const int tid  = threadIdx.x;
    const int lane = tid & 63;
    const int w    = tid >> 6;
    const int g    = lane >> 4;
    const int r16  = lane & 15;

    const size_t base = (size_t)bh * (SEQ * HD);

    // staging thread assignments (fixed per thread)
    const int k_kvo = tid >> 2;
    const int k_o   = k_kvo & 31;
    const int k_row = (k_kvo & 32) + 16 * ((k_o >> 2) & 1) + 4 * (k_o >> 3) + (k_o & 3);
    const int k_dc  = (tid & 3) * 2;
    const int v_kv0 = (tid & 31) * 2;
    const int v_db  = (tid >> 5) * 8;

    // ones bf16 fragment for MFMA row-sum of P
    short8 ones;
    { union { short8 s; unsigned u[4]; } o_;
      o_.u[0] = o_.u[1] = o_.u[2] = o_.u[3] = 0x3F803F80u; ones = o_.s; }

    // prefetch registers (held across compute)
    f32x4 ka0, ka1, kb0, kb1, va0, va1, vb0, vb1;

    auto LOADT = [&](int kvbase) {
        const float* kp = K + base + (size_t)(kvbase + k_kvo) * HD + k_dc * 8;
        ka0 = *(const f32x4*)(kp + 0);
        ka1 = *(const f32x4*)(kp + 4);
        kb0 = *(const f32x4*)(kp + 8);
        kb1 = *(const f32x4*)(kp + 12);
        const float* vp = V + base + (size_t)(kvbase + v_kv0) * HD + v_db;
        va0 = *(const f32x4*)(vp + 0);
        va1 = *(const f32x4*)(vp + 4);
        vb0 = *(const f32x4*)(vp + HD);
        vb1 = *(const f32x4*)(vp + HD + 4);
    };
    auto WRITET = [&](int b) {
        char* Kl = smraw + b * 16384;
        char* Vl = Kl + 8192;
        union { short8 s; unsigned u[4]; } c0, c1;
        c0.u[0] = pk2(ka0[0], ka0[1]); c0.u[1] = pk2(ka0[2], ka0[3]);
        c0.u[2] = pk2(ka1[0], ka1[1]); c0.u[3] = pk2(ka1[2], ka1[3]);
        c1.u[0] = pk2(kb0[0], kb0[1]); c1.u[1] = pk2(kb0[2], kb0[3]);
        c1.u[2] = pk2(kb1[0], kb1[1]); c1.u[3] = pk2(kb1[2], kb1[3]);
        const int r7 = k_row & 7;
        *(short8*)(Kl + ((k_row * 8 + (k_dc ^ r7)) << 4))       = c0.s;
        *(short8*)(Kl + ((k_row * 8 + ((k_dc + 1) ^ r7)) << 4)) = c1.s;
        const int u  = v_kv0 >> 3;
        const int wo = (v_kv0 & 7) * 2;
        #pragma unroll
        for (int i = 0; i < 4; ++i) {
            const int d = v_db + i;
            *(unsigned*)(Vl + ((d * 8 + (u ^ (d & 7))) << 4) + wo) = pk2(va0[i], vb0[i]);
        }
        #pragma unroll
        for (int i = 0; i < 4; ++i) {
            const int d = v_db + 4 + i;
            *(unsigned*)(Vl + ((d * 8 + (u ^ (d & 7))) << 4) + wo) = pk2(va1[i], vb1[i]);
        }
    };

    const float SC = 0.18033688011112042f;   // 0.125 * log2(e)

    #pragma unroll 1
    for (int tile = 0; tile < 2; ++tile) {
        const int qbase = (tile == 0 ? 15 - p : p) * 128;
        const int wq = qbase + w * 32;

        // ---- Q fragments for this tile ----
        short8 qf[2][2];
        #pragma unroll
        for (int qs = 0; qs < 2; ++qs) {
            const float* qp = Q + base + (size_t)(wq + qs * 16 + r16) * HD + 8 * g;
            #pragma unroll
            for (int c = 0; c < 2; ++c) {
                f32x4 a = *(const f32x4*)(qp + c * 32);
                f32x4 b = *(const f32x4*)(qp + c * 32 + 4);
                union { short8 s; unsigned u[4]; } t;
                t.u[0] = pk2(a[0] * SC, a[1] * SC);
                t.u[1] = pk2(a[2] * SC, a[3] * SC);
                t.u[2] = pk2(b[0] * SC, b[1] * SC);
                t.u[3] = pk2(b[2] * SC, b[3] * SC);
                qf[qs][c] = t.s;
            }
        }

        f32x4 oacc[2][4] = {};
        f32x4 lacc[2] = {};
        float mrun[2] = {-1e30f, -1e30f};

        const int nkvb = (qbase + 128) >> 6;

        __syncthreads();                 // LDS safe to overwrite (tile switch)
        LOADT(0);
        WRITET(0);
        __syncthreads();

        for (int kvb = 0; kvb < nkvb; ++kvb) {
            const int kvbase = kvb << 6;
            const int buf = kvb & 1;
            const bool more = (kvb + 1 < nkvb);

            if (more) LOADT((kvb + 1) << 6);   // issue prefetch loads early

            if (kvbase <= wq + 31) {           // wave-uniform causal activity
                const char* Kl = smraw + buf * 16384;
                const char* Vl = Kl + 8192;

                // ---- QK^T (shared K-fragment reads across q-subtiles) ----
                f32x4 sa[2][2][2];
                #pragma unroll
                for (int qs = 0; qs < 2; ++qs)
                    #pragma unroll
                    for (int c2 = 0; c2 < 2; ++c2)
                        #pragma unroll
                        for (int t = 0; t < 2; ++t)
                            sa[qs][c2][t] = (f32x4){0.f, 0.f, 0.f, 0.f};
                __builtin_amdgcn_s_setprio(1);
                #pragma unroll
                for (int c2 = 0; c2 < 2; ++c2)
                    #pragma unroll
                    for (int t = 0; t < 2; ++t)
                        #pragma unroll
                        for (int c = 0; c < 2; ++c) {
                            const int row = c2 * 32 + t * 16 + r16;
                            short8 kf = *(const short8*)(Kl + ((row * 8 + ((4 * c + g) ^ (row & 7))) << 4));
                            sa[0][c2][t] = __builtin_amdgcn_mfma_f32_16x16x32_bf16(kf, qf[0][c], sa[0][c2][t], 0, 0, 0);
                            sa[1][c2][t] = __builtin_amdgcn_mfma_f32_16x16x32_bf16(kf, qf[1][c], sa[1][c2][t], 0, 0, 0);
                        }
                __builtin_amdgcn_s_setprio(0);

                // ---- causal mask (diagonal region only) ----
                #pragma unroll
                for (int qs = 0; qs < 2; ++qs) {
                    const int q0 = wq + qs * 16;
                    if (kvbase + 63 > q0) {
                        const int qrow = q0 + r16;
                        #pragma unroll
                        for (int c2 = 0; c2 < 2; ++c2)
                            #pragma unroll
                            for (int t = 0; t < 2; ++t)
                                #pragma unroll
                                for (int r = 0; r < 4; ++r) {
                                    const int kv = kvbase + c2 * 32 + 8 * g + 4 * t + r;
                                    if (kv > qrow) sa[qs][c2][t][r] = -1e30f;
                                }
                    }
                }

                // ---- stats + defer-rescale (exp2 domain, THR=8) ----
                float mnew[2];
                #pragma unroll
                for (int qs = 0; qs < 2; ++qs) {
                    float mloc = sa[qs][0][0][0];
                    #pragma unroll
                    for (int c2 = 0; c2 < 2; ++c2)
                        #pragma unroll
                        for (int t = 0; t < 2; ++t)
                            #pragma unroll
                            for (int r = 0; r < 4; ++r)
                                mloc = fmaxf(mloc, sa[qs][c2][t][r]);
                    mloc = fmaxf(mloc, __shfl_xor(mloc, 16));
                    mloc = fmaxf(mloc, __shfl_xor(mloc, 32));
                    mnew[qs] = fmaxf(mrun[qs], mloc);
                }
                if (!__all((mnew[0] - mrun[0] <= 8.0f) && (mnew[1] - mrun[1] <= 8.0f))) {
                    #pragma unroll
                    for (int qs = 0; qs < 2; ++qs) {
                        const float alpha = __builtin_amdgcn_exp2f(mrun[qs] - mnew[qs]);
                        mrun[qs] = mnew[qs];
                        lacc[qs][0] *= alpha;      // only [0] is ever read
                        #pragma unroll
                        for (int dt = 0; dt < 4; ++dt) oacc[qs][dt] *= alpha;
                    }
                }
                #pragma unroll
                for (int qs = 0; qs < 2; ++qs)
                    #pragma unroll
                    for (int c2 = 0; c2 < 2; ++c2)
                        #pragma unroll
                        for (int t = 0; t < 2; ++t)
                            #pragma unroll
                            for (int r = 0; r < 4; ++r)
                                sa[qs][c2][t][r] =
                                    __builtin_amdgcn_exp2f(sa[qs][c2][t][r] - mrun[qs]);

                // ---- PV: O^T += V^T . P ; l += ones . P (MFMA row-sum) ----
                #pragma unroll
                for (int c2 = 0; c2 < 2; ++c2) {
                    union { short8 s; unsigned u[4]; } pf0, pf1;
                    pf0.u[0] = pk2(sa[0][c2][0][0], sa[0][c2][0][1]);
                    pf0.u[1] = pk2(sa[0][c2][0][2], sa[0][c2][0][3]);
                    pf0.u[2] = pk2(sa[0][c2][1][0], sa[0][c2][1][1]);
                    pf0.u[3] = pk2(sa[0][c2][1][2], sa[0][c2][1][3]);
                    pf1.u[0] = pk2(sa[1][c2][0][0], sa[1][c2][0][1]);
                    pf1.u[1] = pk2(sa[1][c2][0][2], sa[1][c2][0][3]);
                    pf1.u[2] = pk2(sa[1][c2][1][0], sa[1][c2][1][1]);
                    pf1.u[3] = pk2(sa[1][c2][1][2], sa[1][c2][1][3]);
                    __builtin_amdgcn_s_setprio(1);
                    lacc[0] = __builtin_amdgcn_mfma_f32_16x16x32_bf16(ones, pf0.s, lacc[0], 0, 0, 0);
                    lacc[1] = __builtin_amdgcn_mfma_f32_16x16x32_bf16(ones, pf1.s, lacc[1], 0, 0, 0);
                    #pragma unroll
                    for (int dt = 0; dt < 4; ++dt) {
                        const int row = dt * 16 + r16;
                        short8 vf = *(const short8*)(Vl + ((row * 8 + ((c2 * 4 + g) ^ (row & 7))) << 4));
                        oacc[0][dt] = __builtin_amdgcn_mfma_f32_16x16x32_bf16(vf, pf0.s, oacc[0][dt], 0, 0, 0);
                        oacc[1][dt] = __builtin_amdgcn_mfma_f32_16x16x32_bf16(vf, pf1.s, oacc[1][dt], 0, 0, 0);
                    }
                    __builtin_amdgcn_s_setprio(0);
                }
            }

            if (more) {
                WRITET(buf ^ 1);               // cvt+write prefetched tile
                __syncthreads();
            }
        }

        // ---- epilogue: direct coalesced stores from the accumulator ----
        #pragma unroll
        for (int qs = 0; qs < 2; ++qs) {
            const float inv = 1.0f / lacc[qs][0];
            float* op = O + base + (size_t)(wq + qs * 16 + r16) * HD + 4 * g;
            #pragma unroll
            for (int dt = 0; dt < 4; ++dt) {
                f32x4 vv = oacc[qs][dt] * inv;
                *(f32x4*)(op + dt * 16) = vv;
            }
        }
    }
}

extern "C" void kernel_launch(void* const* d_in, const int* in_sizes, int n_in,
                              void* d_out, int out_size, void* d_ws, size_t ws_size,
                              hipStream_t stream) {
    (void)in_sizes; (void)n_in; (void)out_size; (void)d_ws; (void)ws_size;
    const float* q = (const float*)d_in[0];
    const float* k = (const float*)d_in[1];
    const float* v = (const float*)d_in[2];
    float* o = (float*)d_out;
    sdpa_kernel<<<dim3(64 * 8), dim3(256), 0, stream>>>(q, k, v, o);
}